// Round 2
// baseline (194.856 us; speedup 1.0000x reference)
//
#include <hip/hip_runtime.h>

#define NEG_SLOPE 0.01f
#define B_ 8
#define N_ 2048
#define F_ 512
#define M_ (B_ * N_)   // 16384

typedef unsigned short u16;
typedef __attribute__((ext_vector_type(8))) unsigned short u16x8;
typedef __attribute__((ext_vector_type(8))) __bf16 bf16x8;
typedef __attribute__((ext_vector_type(4))) float f32x4;

__device__ __forceinline__ u16 f2bf(float f) {
    unsigned u = __float_as_uint(f);
    u += 0x7FFFu + ((u >> 16) & 1u);   // RNE (values finite)
    return (u16)(u >> 16);
}
__device__ __forceinline__ float bf2f(u16 h) {
    return __uint_as_float(((unsigned)h) << 16);
}

__device__ __forceinline__ f32x4 mfma16(u16x8 a, u16x8 b, f32x4 c) {
    return __builtin_amdgcn_mfma_f32_16x16x32_bf16(
        __builtin_bit_cast(bf16x8, a), __builtin_bit_cast(bf16x8, b), c, 0, 0, 0);
}

__device__ __forceinline__ void load_lds16(const void* g, void* l) {
    __builtin_amdgcn_global_load_lds(
        (__attribute__((address_space(1))) void*)(void*)g,
        (__attribute__((address_space(3))) void*)l, 16, 0, 0);
}

// ---------------- Wk fp32 [K][N] -> bf16 hi/lo transposed [N][K] ----------------
__global__ __launch_bounds__(256) void convert_wkt(const float* __restrict__ Wk,
                                                   u16* __restrict__ Whi,
                                                   u16* __restrict__ Wlo) {
    const int id = blockIdx.x * 256 + threadIdx.x;  // 262144 threads
    const int k = id & 511;
    const int n = id >> 9;
    const float f = Wk[k * 512 + n];
    const u16 h = f2bf(f);
    Whi[id] = h;
    Wlo[id] = f2bf(f - bf2f(h));
}

// ---- feat = X @ Wk + bk, split-bf16 (hi/lo) MFMA for ~fp32 accuracy, fp32 out ----
__global__ __launch_bounds__(256) void gemm_feat(const float* __restrict__ X,
                                                 const u16* __restrict__ Whi,
                                                 const u16* __restrict__ Wlo,
                                                 const float* __restrict__ bk,
                                                 float* __restrict__ feat) {
    __shared__ u16 Ah[128 * 64];
    __shared__ u16 Al[128 * 64];
    __shared__ u16 Bh[128 * 64];
    __shared__ u16 Bl[128 * 64];
    const int t = threadIdx.x;
    const int lane = t & 63;
    const int w = t >> 6;
    const int tm = blockIdx.x >> 2;   // 0..127 (M tiles)
    const int tn = blockIdx.x & 3;    // 0..3   (N tiles)
    const int wr = w >> 1, wc = w & 1;

    f32x4 acc[4][4];
#pragma unroll
    for (int m = 0; m < 4; ++m)
#pragma unroll
        for (int n = 0; n < 4; ++n) acc[m][n] = {0.f, 0.f, 0.f, 0.f};

    // B staging via global_load_lds (wave-uniform LDS base + lane*16)
    const int lrow = lane >> 3;
    const int lcol = (lane & 7) * 8;
    const u16* BhBase = Whi + ((size_t)(tn * 128 + w * 8 + lrow)) * 512 + lcol;
    const u16* BlBase = Wlo + ((size_t)(tn * 128 + w * 8 + lrow)) * 512 + lcol;
    u16* BhW = Bh + (w * 8) * 64;
    u16* BlW = Bl + (w * 8) * 64;

    // A reg-staging: thread t covers 8 consecutive k of row (t>>3) (+32 rows/pass)
    const int arow = t >> 3;
    const int akk = (t & 7) * 8;
    const float* Abase = X + ((size_t)(tm * 128 + arow)) * 512 + akk;
    u16* AhW = Ah + arow * 64 + akk;
    u16* AlW = Al + arow * 64 + akk;

    for (int k0 = 0; k0 < 512; k0 += 64) {
#pragma unroll
        for (int iss = 0; iss < 4; ++iss) {
            load_lds16(BhBase + (size_t)(iss * 32) * 512 + k0, BhW + iss * 32 * 64);
            load_lds16(BlBase + (size_t)(iss * 32) * 512 + k0, BlW + iss * 32 * 64);
        }
#pragma unroll
        for (int p = 0; p < 4; ++p) {
            const float4 x0 = *(const float4*)(Abase + (size_t)(p * 32) * 512 + k0);
            const float4 x1 = *(const float4*)(Abase + (size_t)(p * 32) * 512 + k0 + 4);
            const float xv[8] = {x0.x, x0.y, x0.z, x0.w, x1.x, x1.y, x1.z, x1.w};
            u16x8 hi, lo;
#pragma unroll
            for (int e = 0; e < 8; ++e) {
                const u16 h = f2bf(xv[e]);
                hi[e] = h;
                lo[e] = f2bf(xv[e] - bf2f(h));
            }
            *(u16x8*)(AhW + p * 32 * 64) = hi;
            *(u16x8*)(AlW + p * 32 * 64) = lo;
        }
        __syncthreads();
#pragma unroll
        for (int kk = 0; kk < 64; kk += 32) {
            u16x8 ah[4], al[4], bh[4], bl[4];
            const int aoff = kk + (lane >> 4) * 8;
#pragma unroll
            for (int m = 0; m < 4; ++m) {
                const int r = (wr * 64 + m * 16 + (lane & 15)) * 64 + aoff;
                ah[m] = *(const u16x8*)(Ah + r);
                al[m] = *(const u16x8*)(Al + r);
            }
#pragma unroll
            for (int n = 0; n < 4; ++n) {
                const int r = (wc * 64 + n * 16 + (lane & 15)) * 64 + aoff;
                bh[n] = *(const u16x8*)(Bh + r);
                bl[n] = *(const u16x8*)(Bl + r);
            }
#pragma unroll
            for (int m = 0; m < 4; ++m)
#pragma unroll
                for (int n = 0; n < 4; ++n) {
                    acc[m][n] = mfma16(ah[m], bh[n], acc[m][n]);
                    acc[m][n] = mfma16(ah[m], bl[n], acc[m][n]);
                    acc[m][n] = mfma16(al[m], bh[n], acc[m][n]);
                }
        }
        __syncthreads();
    }

    const int crow0 = tm * 128 + wr * 64;
    const int ccol0 = tn * 128 + wc * 64;
#pragma unroll
    for (int n = 0; n < 4; ++n) {
        const int gc = ccol0 + n * 16 + (lane & 15);
        const float bkv = bk[gc];
#pragma unroll
        for (int m = 0; m < 4; ++m) {
            const int gr = crow0 + m * 16 + (lane >> 4) * 4;
#pragma unroll
            for (int r = 0; r < 4; ++r)
                feat[(size_t)(gr + r) * 512 + gc] = acc[m][n][r] + bkv;
        }
    }
}

// ---------------- a_self / a_neigh : per-row dots of fp32 feat ----------------
__global__ __launch_bounds__(256) void dots(const float* __restrict__ feat,
                                            const float* __restrict__ ws,
                                            const float* __restrict__ bs,
                                            const float* __restrict__ wn,
                                            const float* __restrict__ bn,
                                            float* __restrict__ a_self,
                                            float* __restrict__ a_neigh) {
    const int t = threadIdx.x, lane = t & 63, w = t >> 6;
    const int row = blockIdx.x * 4 + w;
    const float4 f0 = *(const float4*)(feat + (size_t)row * 512 + lane * 8);
    const float4 f1 = *(const float4*)(feat + (size_t)row * 512 + lane * 8 + 4);
    const float fv[8] = {f0.x, f0.y, f0.z, f0.w, f1.x, f1.y, f1.z, f1.w};
    const float4 sa = *(const float4*)(ws + lane * 8);
    const float4 sb = *(const float4*)(ws + lane * 8 + 4);
    const float4 na = *(const float4*)(wn + lane * 8);
    const float4 nb = *(const float4*)(wn + lane * 8 + 4);
    float ds = fv[0] * sa.x + fv[1] * sa.y + fv[2] * sa.z + fv[3] * sa.w +
               fv[4] * sb.x + fv[5] * sb.y + fv[6] * sb.z + fv[7] * sb.w;
    float dn = fv[0] * na.x + fv[1] * na.y + fv[2] * na.z + fv[3] * na.w +
               fv[4] * nb.x + fv[5] * nb.y + fv[6] * nb.z + fv[7] * nb.w;
#pragma unroll
    for (int m = 32; m; m >>= 1) {
        ds += __shfl_xor(ds, m);
        dn += __shfl_xor(dn, m);
    }
    if (lane == 0) {
        a_self[row] = ds + bs[0];
        a_neigh[row] = dn + bn[0];
    }
}

// ------- per-row sparse softmax + fp32 PV gather + tanh + 8x replicated write -------
__global__ __launch_bounds__(256) void attn_row(const float* __restrict__ A,
                                                const float* __restrict__ feat,
                                                const float* __restrict__ a_self,
                                                const float* __restrict__ a_neigh,
                                                float* __restrict__ out) {
    const int row = blockIdx.x;        // 0..16383
    const int b = row >> 11;
    const int t = threadIdx.x;
    const int lane = t & 63, w = t >> 6;

    __shared__ int   lj[N_];
    __shared__ float lsv[N_];
    __shared__ int   scan[256];
    __shared__ float red[8];
    __shared__ float nfw[4][F_];

    const float asi = a_self[row];

    // phase 1: scan A row; per-thread contiguous 8-col segment (deterministic)
    const float4* Arow = (const float4*)(A + (size_t)row * N_);
    const float4* An   = (const float4*)(a_neigh + b * N_);
    const float4 a0 = Arow[t * 2], a1 = Arow[t * 2 + 1];
    const float4 n0 = An[t * 2],   n1 = An[t * 2 + 1];
    const float av[8] = {a0.x, a0.y, a0.z, a0.w, a1.x, a1.y, a1.z, a1.w};
    const float nv[8] = {n0.x, n0.y, n0.z, n0.w, n1.x, n1.y, n1.z, n1.w};
    float sv[8];
    int cnt = 0;
    float mloc = -3.0e38f;
#pragma unroll
    for (int e = 0; e < 8; ++e) {
        float s = asi * nv[e];
        s = s > 0.f ? s : NEG_SLOPE * s;
        sv[e] = s;
        if (av[e] != 0.f) { ++cnt; mloc = fmaxf(mloc, s); }
    }
    scan[t] = cnt;
    __syncthreads();
    for (int off = 1; off < 256; off <<= 1) {   // Hillis-Steele inclusive scan
        const int vo = scan[t];
        const int ad = (t >= off) ? scan[t - off] : 0;
        __syncthreads();
        scan[t] = vo + ad;
        __syncthreads();
    }
    int pos = scan[t] - cnt;
    const int total = scan[255];
#pragma unroll
    for (int e = 0; e < 8; ++e) {
        if (av[e] != 0.f) { lj[pos] = t * 8 + e; lsv[pos] = sv[e]; ++pos; }
    }
#pragma unroll
    for (int m = 32; m; m >>= 1) mloc = fmaxf(mloc, __shfl_xor(mloc, m));
    if (lane == 0) red[w] = mloc;
    __syncthreads();
    const float mx = fmaxf(fmaxf(red[0], red[1]), fmaxf(red[2], red[3]));

    // phase 2: exp + denom
    float ssum = 0.f;
    for (int k = t; k < total; k += 256) {
        const float wv = __expf(lsv[k] - mx);
        lsv[k] = wv;
        ssum += wv;
    }
#pragma unroll
    for (int m = 32; m; m >>= 1) ssum += __shfl_xor(ssum, m);
    if (lane == 0) red[4 + w] = ssum;
    __syncthreads();
    const float inv = 1.f / (red[4] + red[5] + red[6] + red[7]);

    // phase 3: PV gather (fp32 feat) — wave-strided list entries, lane owns 8 features
    const float* frow = feat + (size_t)b * N_ * F_ + lane * 8;
    float acc[8] = {0.f, 0.f, 0.f, 0.f, 0.f, 0.f, 0.f, 0.f};
    int k = w;
    for (; k + 4 < total; k += 8) {
        const size_t j0 = (size_t)lj[k] * F_, j1 = (size_t)lj[k + 4] * F_;
        const float p0 = lsv[k], p1 = lsv[k + 4];
        const float4 v0a = *(const float4*)(frow + j0);
        const float4 v0b = *(const float4*)(frow + j0 + 4);
        const float4 v1a = *(const float4*)(frow + j1);
        const float4 v1b = *(const float4*)(frow + j1 + 4);
        acc[0] += p0 * v0a.x + p1 * v1a.x;
        acc[1] += p0 * v0a.y + p1 * v1a.y;
        acc[2] += p0 * v0a.z + p1 * v1a.z;
        acc[3] += p0 * v0a.w + p1 * v1a.w;
        acc[4] += p0 * v0b.x + p1 * v1b.x;
        acc[5] += p0 * v0b.y + p1 * v1b.y;
        acc[6] += p0 * v0b.z + p1 * v1b.z;
        acc[7] += p0 * v0b.w + p1 * v1b.w;
    }
    if (k < total) {
        const size_t j0 = (size_t)lj[k] * F_;
        const float p0 = lsv[k];
        const float4 v0a = *(const float4*)(frow + j0);
        const float4 v0b = *(const float4*)(frow + j0 + 4);
        acc[0] += p0 * v0a.x; acc[1] += p0 * v0a.y;
        acc[2] += p0 * v0a.z; acc[3] += p0 * v0a.w;
        acc[4] += p0 * v0b.x; acc[5] += p0 * v0b.y;
        acc[6] += p0 * v0b.z; acc[7] += p0 * v0b.w;
    }
#pragma unroll
    for (int e = 0; e < 8; ++e) nfw[w][lane * 8 + e] = acc[e];
    __syncthreads();

    // phase 4: cross-wave sum, tanh, write 8 identical heads
    const int f0 = t * 2;
    const float nf0 = (nfw[0][f0] + nfw[1][f0]) + (nfw[2][f0] + nfw[3][f0]);
    const float nf1 = (nfw[0][f0 + 1] + nfw[1][f0 + 1]) + (nfw[2][f0 + 1] + nfw[3][f0 + 1]);
    const float o0 = tanhf(nf0 * inv);
    const float o1 = tanhf(nf1 * inv);
    const float2 o = make_float2(o0, o1);
    float* obase = out + (size_t)row * (8 * F_) + f0;
#pragma unroll
    for (int h = 0; h < 8; ++h) *(float2*)(obase + h * F_) = o;
}

extern "C" void kernel_launch(void* const* d_in, const int* in_sizes, int n_in,
                              void* d_out, int out_size, void* d_ws, size_t ws_size,
                              hipStream_t stream) {
    const float* X  = (const float*)d_in[0];
    const float* A  = (const float*)d_in[1];
    const float* Wk = (const float*)d_in[2];
    const float* bk = (const float*)d_in[3];
    const float* ws = (const float*)d_in[4];
    const float* bs = (const float*)d_in[5];
    const float* wn = (const float*)d_in[6];
    const float* bn = (const float*)d_in[7];
    float* out = (float*)d_out;

    char* wsb = (char*)d_ws;
    float* feat    = (float*)(wsb);                      // 32 MiB (fp32)
    u16* Whi       = (u16*)(wsb + 33554432);             // 0.5 MiB
    u16* Wlo       = (u16*)(wsb + 34078720);             // 0.5 MiB
    float* a_self  = (float*)(wsb + 34603008);           // 64 KiB
    float* a_neigh = (float*)(wsb + 34668544);           // 64 KiB

    convert_wkt<<<dim3(1024),  dim3(256), 0, stream>>>(Wk, Whi, Wlo);
    gemm_feat  <<<dim3(512),   dim3(256), 0, stream>>>(X, Whi, Wlo, bk, feat);
    dots       <<<dim3(4096),  dim3(256), 0, stream>>>(feat, ws, bs, wn, bn, a_self, a_neigh);
    attn_row   <<<dim3(16384), dim3(256), 0, stream>>>(A, feat, a_self, a_neigh, out);
}

// Round 3
// 161.883 us; speedup vs baseline: 1.2037x; 1.2037x over previous
//
#include <hip/hip_runtime.h>

#define NEG_SLOPE 0.01f
#define B_ 8
#define N_ 2048
#define F_ 512
#define M_ (B_ * N_)   // 16384

typedef unsigned short u16;
typedef __attribute__((ext_vector_type(8))) unsigned short u16x8;
typedef __attribute__((ext_vector_type(8))) __bf16 bf16x8;
typedef __attribute__((ext_vector_type(4))) float f32x4;

__device__ __forceinline__ u16 f2bf(float f) {
    unsigned u = __float_as_uint(f);
    u += 0x7FFFu + ((u >> 16) & 1u);   // RNE (values finite)
    return (u16)(u >> 16);
}
__device__ __forceinline__ float bf2f(u16 h) {
    return __uint_as_float(((unsigned)h) << 16);
}

__device__ __forceinline__ f32x4 mfma16(u16x8 a, u16x8 b, f32x4 c) {
    return __builtin_amdgcn_mfma_f32_16x16x32_bf16(
        __builtin_bit_cast(bf16x8, a), __builtin_bit_cast(bf16x8, b), c, 0, 0, 0);
}

__device__ __forceinline__ void load_lds16(const void* g, void* l) {
    __builtin_amdgcn_global_load_lds(
        (__attribute__((address_space(1))) void*)(void*)g,
        (__attribute__((address_space(3))) void*)l, 16, 0, 0);
}

// ---------------- Wk fp32 [K][N] -> bf16 hi/lo transposed [N][K] ----------------
__global__ __launch_bounds__(256) void convert_wkt(const float* __restrict__ Wk,
                                                   u16* __restrict__ Whi,
                                                   u16* __restrict__ Wlo) {
    const int id = blockIdx.x * 256 + threadIdx.x;  // 262144 threads
    const int k = id & 511;
    const int n = id >> 9;
    const float f = Wk[k * 512 + n];
    const u16 h = f2bf(f);
    Whi[id] = h;
    Wlo[id] = f2bf(f - bf2f(h));
}

// -------- prep: ws2 = Wk @ ws, wn2 = Wk @ wn, csn = {bk.ws+bs, bk.wn+bn} --------
__global__ __launch_bounds__(256) void prep(const float* __restrict__ Wk,
                                            const float* __restrict__ bk,
                                            const float* __restrict__ ws,
                                            const float* __restrict__ bs,
                                            const float* __restrict__ wn,
                                            const float* __restrict__ bn,
                                            float* __restrict__ ws2,
                                            float* __restrict__ wn2,
                                            float* __restrict__ csn) {
    const int t = threadIdx.x, lane = t & 63, w = t >> 6;
    const int bid = blockIdx.x;
    if (bid >= 256) {                       // scalar blocks
        if (w == 0) {
            const int sel = bid - 256;      // 0: self, 1: neigh
            const float* vec = sel ? wn : ws;
            const float4 b0 = *(const float4*)(bk + lane * 8);
            const float4 b1 = *(const float4*)(bk + lane * 8 + 4);
            const float4 v0 = *(const float4*)(vec + lane * 8);
            const float4 v1 = *(const float4*)(vec + lane * 8 + 4);
            float d = b0.x * v0.x + b0.y * v0.y + b0.z * v0.z + b0.w * v0.w +
                      b1.x * v1.x + b1.y * v1.y + b1.z * v1.z + b1.w * v1.w;
#pragma unroll
            for (int m = 32; m; m >>= 1) d += __shfl_xor(d, m);
            if (lane == 0) csn[sel] = d + (sel ? bn[0] : bs[0]);
        }
        return;
    }
    const int W = bid * 4 + w;              // 0..1023
    const int k = W & 511;
    const float* vec = (W < 512) ? ws : wn;
    const float4 w0 = *(const float4*)(Wk + (size_t)k * 512 + lane * 8);
    const float4 w1 = *(const float4*)(Wk + (size_t)k * 512 + lane * 8 + 4);
    const float4 v0 = *(const float4*)(vec + lane * 8);
    const float4 v1 = *(const float4*)(vec + lane * 8 + 4);
    float d = w0.x * v0.x + w0.y * v0.y + w0.z * v0.z + w0.w * v0.w +
              w1.x * v1.x + w1.y * v1.y + w1.z * v1.z + w1.w * v1.w;
#pragma unroll
    for (int m = 32; m; m >>= 1) d += __shfl_xor(d, m);
    if (lane == 0) ((W < 512) ? ws2 : wn2)[k] = d;
}

// -------- a_self/a_neigh straight from X (fp32-exact): a = X.ws2 + csn --------
__global__ __launch_bounds__(256) void dots_x(const float* __restrict__ X,
                                              const float* __restrict__ ws2,
                                              const float* __restrict__ wn2,
                                              const float* __restrict__ csn,
                                              float* __restrict__ a_self,
                                              float* __restrict__ a_neigh) {
    const int t = threadIdx.x, lane = t & 63, w = t >> 6;
    const int row = blockIdx.x * 4 + w;
    const float4 f0 = *(const float4*)(X + (size_t)row * 512 + lane * 8);
    const float4 f1 = *(const float4*)(X + (size_t)row * 512 + lane * 8 + 4);
    const float fv[8] = {f0.x, f0.y, f0.z, f0.w, f1.x, f1.y, f1.z, f1.w};
    const float4 sa = *(const float4*)(ws2 + lane * 8);
    const float4 sb = *(const float4*)(ws2 + lane * 8 + 4);
    const float4 na = *(const float4*)(wn2 + lane * 8);
    const float4 nb = *(const float4*)(wn2 + lane * 8 + 4);
    float ds = fv[0] * sa.x + fv[1] * sa.y + fv[2] * sa.z + fv[3] * sa.w +
               fv[4] * sb.x + fv[5] * sb.y + fv[6] * sb.z + fv[7] * sb.w;
    float dn = fv[0] * na.x + fv[1] * na.y + fv[2] * na.z + fv[3] * na.w +
               fv[4] * nb.x + fv[5] * nb.y + fv[6] * nb.z + fv[7] * nb.w;
#pragma unroll
    for (int m = 32; m; m >>= 1) {
        ds += __shfl_xor(ds, m);
        dn += __shfl_xor(dn, m);
    }
    if (lane == 0) {
        a_self[row] = ds + csn[0];
        a_neigh[row] = dn + csn[1];
    }
}

// ---- feat = X @ Wk + bk, split-bf16 (hi/lo) MFMA, bf16 out ----
__global__ __launch_bounds__(256) void gemm_feat(const float* __restrict__ X,
                                                 const u16* __restrict__ Whi,
                                                 const u16* __restrict__ Wlo,
                                                 const float* __restrict__ bk,
                                                 u16* __restrict__ feat) {
    __shared__ u16 Ah[128 * 64];
    __shared__ u16 Al[128 * 64];
    __shared__ u16 Bh[128 * 64];
    __shared__ u16 Bl[128 * 64];
    const int t = threadIdx.x;
    const int lane = t & 63;
    const int w = t >> 6;
    // XCD swizzle: 4 tn-siblings (shared A-tile) land on one XCD
    const int bid = blockIdx.x;
    const int tm = (bid & 7) * 16 + (bid >> 5);   // 0..127
    const int tn = (bid >> 3) & 3;                // 0..3
    const int wr = w >> 1, wc = w & 1;

    f32x4 acc[4][4];
#pragma unroll
    for (int m = 0; m < 4; ++m)
#pragma unroll
        for (int n = 0; n < 4; ++n) acc[m][n] = {0.f, 0.f, 0.f, 0.f};

    // B staging via global_load_lds (wave-uniform LDS base + lane*16)
    const int lrow = lane >> 3;
    const int lcol = (lane & 7) * 8;
    const u16* BhBase = Whi + ((size_t)(tn * 128 + w * 8 + lrow)) * 512 + lcol;
    const u16* BlBase = Wlo + ((size_t)(tn * 128 + w * 8 + lrow)) * 512 + lcol;
    u16* BhW = Bh + (w * 8) * 64;
    u16* BlW = Bl + (w * 8) * 64;

    // A reg-staging: thread t covers 8 consecutive k of row (t>>3) (+32 rows/pass)
    const int arow = t >> 3;
    const int akk = (t & 7) * 8;
    const float* Abase = X + ((size_t)(tm * 128 + arow)) * 512 + akk;
    u16* AhW = Ah + arow * 64 + akk;
    u16* AlW = Al + arow * 64 + akk;

    for (int k0 = 0; k0 < 512; k0 += 64) {
#pragma unroll
        for (int iss = 0; iss < 4; ++iss) {
            load_lds16(BhBase + (size_t)(iss * 32) * 512 + k0, BhW + iss * 32 * 64);
            load_lds16(BlBase + (size_t)(iss * 32) * 512 + k0, BlW + iss * 32 * 64);
        }
#pragma unroll
        for (int p = 0; p < 4; ++p) {
            const float4 x0 = *(const float4*)(Abase + (size_t)(p * 32) * 512 + k0);
            const float4 x1 = *(const float4*)(Abase + (size_t)(p * 32) * 512 + k0 + 4);
            const float xv[8] = {x0.x, x0.y, x0.z, x0.w, x1.x, x1.y, x1.z, x1.w};
            u16x8 hi, lo;
#pragma unroll
            for (int e = 0; e < 8; ++e) {
                const u16 h = f2bf(xv[e]);
                hi[e] = h;
                lo[e] = f2bf(xv[e] - bf2f(h));
            }
            *(u16x8*)(AhW + p * 32 * 64) = hi;
            *(u16x8*)(AlW + p * 32 * 64) = lo;
        }
        __syncthreads();
#pragma unroll
        for (int kk = 0; kk < 64; kk += 32) {
            u16x8 ah[4], al[4], bh[4], bl[4];
            const int aoff = kk + (lane >> 4) * 8;
#pragma unroll
            for (int m = 0; m < 4; ++m) {
                const int r = (wr * 64 + m * 16 + (lane & 15)) * 64 + aoff;
                ah[m] = *(const u16x8*)(Ah + r);
                al[m] = *(const u16x8*)(Al + r);
            }
#pragma unroll
            for (int n = 0; n < 4; ++n) {
                const int r = (wc * 64 + n * 16 + (lane & 15)) * 64 + aoff;
                bh[n] = *(const u16x8*)(Bh + r);
                bl[n] = *(const u16x8*)(Bl + r);
            }
#pragma unroll
            for (int m = 0; m < 4; ++m)
#pragma unroll
                for (int n = 0; n < 4; ++n) {
                    acc[m][n] = mfma16(ah[m], bh[n], acc[m][n]);
                    acc[m][n] = mfma16(ah[m], bl[n], acc[m][n]);
                    acc[m][n] = mfma16(al[m], bh[n], acc[m][n]);
                }
        }
        __syncthreads();
    }

    const int crow0 = tm * 128 + wr * 64;
    const int ccol0 = tn * 128 + wc * 64;
#pragma unroll
    for (int n = 0; n < 4; ++n) {
        const int gc = ccol0 + n * 16 + (lane & 15);
        const float bkv = bk[gc];
#pragma unroll
        for (int m = 0; m < 4; ++m) {
            const int gr = crow0 + m * 16 + (lane >> 4) * 4;
#pragma unroll
            for (int r = 0; r < 4; ++r)
                feat[(size_t)(gr + r) * 512 + gc] = f2bf(acc[m][n][r] + bkv);
        }
    }
}

// ------- per-row sparse softmax + bf16 PV gather + tanh + 8x replicated write -------
__global__ __launch_bounds__(256) void attn_row(const float* __restrict__ A,
                                                const u16* __restrict__ feat,
                                                const float* __restrict__ a_self,
                                                const float* __restrict__ a_neigh,
                                                float* __restrict__ out) {
    const int bid = blockIdx.x;
    const int row = (bid & 7) * N_ + (bid >> 3);  // XCD b <- batch b (L2 locality)
    const int b = bid & 7;
    const int t = threadIdx.x;
    const int lane = t & 63, w = t >> 6;

    __shared__ int   lj[N_];
    __shared__ float lsv[N_];
    __shared__ int   wtot[4];
    __shared__ float wred[8];
    __shared__ float nfw[4][F_];

    const float asi = a_self[row];

    // phase 1: scan A row; per-thread contiguous 8-col segment (deterministic)
    const float4* Arow = (const float4*)(A + (size_t)row * N_);
    const float4* An   = (const float4*)(a_neigh + b * N_);
    const float4 a0 = Arow[t * 2], a1 = Arow[t * 2 + 1];
    const float4 n0 = An[t * 2],   n1 = An[t * 2 + 1];
    const float av[8] = {a0.x, a0.y, a0.z, a0.w, a1.x, a1.y, a1.z, a1.w};
    const float nv[8] = {n0.x, n0.y, n0.z, n0.w, n1.x, n1.y, n1.z, n1.w};
    float sv[8];
    int cnt = 0;
    float mloc = -3.0e38f;
#pragma unroll
    for (int e = 0; e < 8; ++e) {
        float s = asi * nv[e];
        s = s > 0.f ? s : NEG_SLOPE * s;
        sv[e] = s;
        if (av[e] != 0.f) { ++cnt; mloc = fmaxf(mloc, s); }
    }
    // wave-level inclusive scan (shfl, no barriers)
    int v = cnt;
#pragma unroll
    for (int off = 1; off < 64; off <<= 1) {
        const int u = __shfl_up(v, off);
        if (lane >= off) v += u;
    }
#pragma unroll
    for (int m = 32; m; m >>= 1) mloc = fmaxf(mloc, __shfl_xor(mloc, m));
    if (lane == 63) wtot[w] = v;
    if (lane == 0) wred[w] = mloc;
    __syncthreads();
    int base = v - cnt;
#pragma unroll
    for (int i = 0; i < 4; ++i) base += (i < w) ? wtot[i] : 0;
    const int total = wtot[0] + wtot[1] + wtot[2] + wtot[3];
    const float mx = fmaxf(fmaxf(wred[0], wred[1]), fmaxf(wred[2], wred[3]));
    int pos = base;
#pragma unroll
    for (int e = 0; e < 8; ++e) {
        if (av[e] != 0.f) { lj[pos] = t * 8 + e; lsv[pos] = sv[e]; ++pos; }
    }
    __syncthreads();

    // phase 2: exp + denom
    float ssum = 0.f;
    for (int k = t; k < total; k += 256) {
        const float wv = __expf(lsv[k] - mx);
        lsv[k] = wv;
        ssum += wv;
    }
#pragma unroll
    for (int m = 32; m; m >>= 1) ssum += __shfl_xor(ssum, m);
    if (lane == 0) wred[4 + w] = ssum;
    __syncthreads();
    const float inv = 1.f / (wred[4] + wred[5] + wred[6] + wred[7]);

    // phase 3: PV gather (bf16 feat, L2-resident slab) — wave-strided entries
    const u16* frow = feat + (size_t)b * N_ * F_ + lane * 8;
    float acc[8] = {0.f, 0.f, 0.f, 0.f, 0.f, 0.f, 0.f, 0.f};
    int k = w;
    for (; k + 4 < total; k += 8) {
        const size_t j0 = (size_t)lj[k] * F_, j1 = (size_t)lj[k + 4] * F_;
        const float p0 = lsv[k], p1 = lsv[k + 4];
        const u16x8 v0 = *(const u16x8*)(frow + j0);
        const u16x8 v1 = *(const u16x8*)(frow + j1);
#pragma unroll
        for (int e = 0; e < 8; ++e) acc[e] += p0 * bf2f(v0[e]) + p1 * bf2f(v1[e]);
    }
    if (k < total) {
        const size_t j0 = (size_t)lj[k] * F_;
        const float p0 = lsv[k];
        const u16x8 v0 = *(const u16x8*)(frow + j0);
#pragma unroll
        for (int e = 0; e < 8; ++e) acc[e] += p0 * bf2f(v0[e]);
    }
#pragma unroll
    for (int e = 0; e < 8; ++e) nfw[w][lane * 8 + e] = acc[e];
    __syncthreads();

    // phase 4: cross-wave sum, tanh, write 8 identical heads
    const int f0 = t * 2;
    const float nf0 = (nfw[0][f0] + nfw[1][f0]) + (nfw[2][f0] + nfw[3][f0]);
    const float nf1 = (nfw[0][f0 + 1] + nfw[1][f0 + 1]) + (nfw[2][f0 + 1] + nfw[3][f0 + 1]);
    const float o0 = tanhf(nf0 * inv);
    const float o1 = tanhf(nf1 * inv);
    const float2 o = make_float2(o0, o1);
    float* obase = out + (size_t)row * (8 * F_) + f0;
#pragma unroll
    for (int h = 0; h < 8; ++h) *(float2*)(obase + h * F_) = o;
}

extern "C" void kernel_launch(void* const* d_in, const int* in_sizes, int n_in,
                              void* d_out, int out_size, void* d_ws, size_t ws_size,
                              hipStream_t stream) {
    const float* X  = (const float*)d_in[0];
    const float* A  = (const float*)d_in[1];
    const float* Wk = (const float*)d_in[2];
    const float* bk = (const float*)d_in[3];
    const float* ws = (const float*)d_in[4];
    const float* bs = (const float*)d_in[5];
    const float* wn = (const float*)d_in[6];
    const float* bn = (const float*)d_in[7];
    float* out = (float*)d_out;

    char* wsb = (char*)d_ws;
    u16*   feat    = (u16*)(wsb);                  // 16 MiB (bf16)
    u16*   Whi     = (u16*)(wsb + 16777216);       // 0.5 MiB
    u16*   Wlo     = (u16*)(wsb + 17301504);       // 0.5 MiB
    float* a_self  = (float*)(wsb + 17825792);     // 64 KiB
    float* a_neigh = (float*)(wsb + 17891328);     // 64 KiB
    float* ws2     = (float*)(wsb + 17956864);     // 2 KiB
    float* wn2     = (float*)(wsb + 17958912);     // 2 KiB
    float* csn     = (float*)(wsb + 17960960);     // 8 B

    convert_wkt<<<dim3(1024),  dim3(256), 0, stream>>>(Wk, Whi, Wlo);
    prep       <<<dim3(258),   dim3(256), 0, stream>>>(Wk, bk, ws, bs, wn, bn, ws2, wn2, csn);
    dots_x     <<<dim3(4096),  dim3(256), 0, stream>>>(X, ws2, wn2, csn, a_self, a_neigh);
    gemm_feat  <<<dim3(512),   dim3(256), 0, stream>>>(X, Whi, Wlo, bk, feat);
    attn_row   <<<dim3(16384), dim3(256), 0, stream>>>(A, feat, a_self, a_neigh, out);
}

// Round 4
// 146.174 us; speedup vs baseline: 1.3330x; 1.1075x over previous
//
#include <hip/hip_runtime.h>

#define NEG_SLOPE 0.01f
#define B_ 8
#define N_ 2048
#define F_ 512

typedef unsigned short u16;
typedef __attribute__((ext_vector_type(8))) unsigned short u16x8;
typedef __attribute__((ext_vector_type(8))) _Float16 f16x8;
typedef __attribute__((ext_vector_type(4))) float f32x4;

__device__ __forceinline__ f32x4 mfma16f(u16x8 a, u16x8 b, f32x4 c) {
    return __builtin_amdgcn_mfma_f32_16x16x32_f16(
        __builtin_bit_cast(f16x8, a), __builtin_bit_cast(f16x8, b), c, 0, 0, 0);
}

__device__ __forceinline__ void load_lds16(const void* g, void* l) {
    __builtin_amdgcn_global_load_lds(
        (__attribute__((address_space(1))) void*)(void*)g,
        (__attribute__((address_space(3))) void*)l, 16, 0, 0);
}

// ---- fused prep: Wk -> f16 transposed [N][K]; ws2 = Wk@ws; wn2 = Wk@wn; csn ----
__global__ __launch_bounds__(256) void prep_all(const float* __restrict__ Wk,
                                                const float* __restrict__ bk,
                                                const float* __restrict__ ws,
                                                const float* __restrict__ bs,
                                                const float* __restrict__ wn,
                                                const float* __restrict__ bn,
                                                u16* __restrict__ Wf,
                                                float* __restrict__ ws2,
                                                float* __restrict__ wn2,
                                                float* __restrict__ csn) {
    const int bid = blockIdx.x, t = threadIdx.x;
    if (bid < 1024) {                        // Wk [k][n] -> f16 WfT [n][k]
        const int id = bid * 256 + t;
        const int k = id & 511, n = id >> 9;
        ((_Float16*)Wf)[id] = (_Float16)Wk[k * 512 + n];
        return;
    }
    const int lane = t & 63, w = t >> 6;
    if (bid >= 1280) {                       // csn = {bk.ws+bs, bk.wn+bn}
        if (w == 0) {
            const int sel = bid - 1280;
            const float* vec = sel ? wn : ws;
            const float4 b0 = *(const float4*)(bk + lane * 8);
            const float4 b1 = *(const float4*)(bk + lane * 8 + 4);
            const float4 v0 = *(const float4*)(vec + lane * 8);
            const float4 v1 = *(const float4*)(vec + lane * 8 + 4);
            float d = b0.x * v0.x + b0.y * v0.y + b0.z * v0.z + b0.w * v0.w +
                      b1.x * v1.x + b1.y * v1.y + b1.z * v1.z + b1.w * v1.w;
#pragma unroll
            for (int m = 32; m; m >>= 1) d += __shfl_xor(d, m);
            if (lane == 0) csn[sel] = d + (sel ? bn[0] : bs[0]);
        }
        return;
    }
    const int W = (bid - 1024) * 4 + w;      // 0..1023
    const int k = W & 511;
    const float* vec = (W < 512) ? ws : wn;
    const float4 w0 = *(const float4*)(Wk + (size_t)k * 512 + lane * 8);
    const float4 w1 = *(const float4*)(Wk + (size_t)k * 512 + lane * 8 + 4);
    const float4 v0 = *(const float4*)(vec + lane * 8);
    const float4 v1 = *(const float4*)(vec + lane * 8 + 4);
    float d = w0.x * v0.x + w0.y * v0.y + w0.z * v0.z + w0.w * v0.w +
              w1.x * v1.x + w1.y * v1.y + w1.z * v1.z + w1.w * v1.w;
#pragma unroll
    for (int m = 32; m; m >>= 1) d += __shfl_xor(d, m);
    if (lane == 0) ((W < 512) ? ws2 : wn2)[k] = d;
}

// ---- feat = X @ Wk + bk : single-pass f16 MFMA, XOR-swizzled LDS, f16 out ----
__global__ __launch_bounds__(256) void gemm_feat(const float* __restrict__ X,
                                                 const u16* __restrict__ Wf,
                                                 const float* __restrict__ bk,
                                                 u16* __restrict__ feat) {
    __shared__ u16 Af[128 * 64];
    __shared__ u16 Bf[128 * 64];
    const int t = threadIdx.x;
    const int lane = t & 63;
    const int w = t >> 6;
    const int bid = blockIdx.x;
    const int tm = (bid & 7) * 16 + (bid >> 5);   // XCD swizzle: tn-siblings co-XCD
    const int tn = (bid >> 3) & 3;
    const int wr = w >> 1, wc = w & 1;

    f32x4 acc[4][4];
#pragma unroll
    for (int m = 0; m < 4; ++m)
#pragma unroll
        for (int n = 0; n < 4; ++n) acc[m][n] = {0.f, 0.f, 0.f, 0.f};

    // B staging via global_load_lds; LDS dest linear, SOURCE pre-swizzled so that
    // LDS(r, c) holds global(r, c ^ ((r&7)*8))   [T2 + m173 pattern]
    const int lrow = lane >> 3;
    const int scol = ((lane & 7) ^ lrow) * 8;
    const u16* Bbase = Wf + ((size_t)(tn * 128 + w * 8 + lrow)) * 512 + scol;
    u16* BfW = Bf + (w * 8) * 64;

    // A reg-staging with swizzled ds_write
    const int arow = t >> 3;
    const int akk = (t & 7) * 8;
    const float* Abase = X + ((size_t)(tm * 128 + arow)) * 512 + akk;
    u16* AfW = Af + arow * 64 + (akk ^ ((arow & 7) * 8));

    for (int k0 = 0; k0 < 512; k0 += 64) {
#pragma unroll
        for (int iss = 0; iss < 4; ++iss)
            load_lds16(Bbase + (size_t)(iss * 32) * 512 + k0, BfW + iss * 32 * 64);
#pragma unroll
        for (int p = 0; p < 4; ++p) {
            const float4 x0 = *(const float4*)(Abase + (size_t)(p * 32) * 512 + k0);
            const float4 x1 = *(const float4*)(Abase + (size_t)(p * 32) * 512 + k0 + 4);
            const float xv[8] = {x0.x, x0.y, x0.z, x0.w, x1.x, x1.y, x1.z, x1.w};
            u16x8 hv;
#pragma unroll
            for (int e = 0; e < 8; ++e)
                hv[e] = __builtin_bit_cast(u16, (_Float16)xv[e]);
            *(u16x8*)(AfW + p * 32 * 64) = hv;
        }
        __syncthreads();
        const int swz = (lane & 7) * 8;    // (r&7)*8 for r = ...(lane&15)
#pragma unroll
        for (int kk = 0; kk < 64; kk += 32) {
            u16x8 af[4], bf[4];
            const int aoff = (kk + (lane >> 4) * 8) ^ swz;
#pragma unroll
            for (int m = 0; m < 4; ++m)
                af[m] = *(const u16x8*)(Af + (wr * 64 + m * 16 + (lane & 15)) * 64 + aoff);
#pragma unroll
            for (int n = 0; n < 4; ++n)
                bf[n] = *(const u16x8*)(Bf + (wc * 64 + n * 16 + (lane & 15)) * 64 + aoff);
#pragma unroll
            for (int m = 0; m < 4; ++m)
#pragma unroll
                for (int n = 0; n < 4; ++n)
                    acc[m][n] = mfma16f(af[m], bf[n], acc[m][n]);
        }
        __syncthreads();
    }

    const int crow0 = tm * 128 + wr * 64;
    const int ccol0 = tn * 128 + wc * 64;
    _Float16* feat16 = (_Float16*)feat;
#pragma unroll
    for (int n = 0; n < 4; ++n) {
        const int gc = ccol0 + n * 16 + (lane & 15);
        const float bkv = bk[gc];
#pragma unroll
        for (int m = 0; m < 4; ++m) {
            const int gr = crow0 + m * 16 + (lane >> 4) * 4;
#pragma unroll
            for (int r = 0; r < 4; ++r)
                feat16[(size_t)(gr + r) * 512 + gc] = (_Float16)(acc[m][n][r] + bkv);
        }
    }
}

// -------- a_self/a_neigh straight from X (fp32-exact): a = X.ws2 + csn --------
__global__ __launch_bounds__(256) void dots_x(const float* __restrict__ X,
                                              const float* __restrict__ ws2,
                                              const float* __restrict__ wn2,
                                              const float* __restrict__ csn,
                                              float* __restrict__ a_self,
                                              float* __restrict__ a_neigh) {
    const int t = threadIdx.x, lane = t & 63, w = t >> 6;
    const int row = blockIdx.x * 4 + w;
    const float4 f0 = *(const float4*)(X + (size_t)row * 512 + lane * 8);
    const float4 f1 = *(const float4*)(X + (size_t)row * 512 + lane * 8 + 4);
    const float fv[8] = {f0.x, f0.y, f0.z, f0.w, f1.x, f1.y, f1.z, f1.w};
    const float4 sa = *(const float4*)(ws2 + lane * 8);
    const float4 sb = *(const float4*)(ws2 + lane * 8 + 4);
    const float4 na = *(const float4*)(wn2 + lane * 8);
    const float4 nb = *(const float4*)(wn2 + lane * 8 + 4);
    float ds = fv[0] * sa.x + fv[1] * sa.y + fv[2] * sa.z + fv[3] * sa.w +
               fv[4] * sb.x + fv[5] * sb.y + fv[6] * sb.z + fv[7] * sb.w;
    float dn = fv[0] * na.x + fv[1] * na.y + fv[2] * na.z + fv[3] * na.w +
               fv[4] * nb.x + fv[5] * nb.y + fv[6] * nb.z + fv[7] * nb.w;
#pragma unroll
    for (int m = 32; m; m >>= 1) {
        ds += __shfl_xor(ds, m);
        dn += __shfl_xor(dn, m);
    }
    if (lane == 0) {
        a_self[row] = ds + csn[0];
        a_neigh[row] = dn + csn[1];
    }
}

// ------- per-row sparse softmax + f16 PV gather + tanh + 8x replicated write -------
__global__ __launch_bounds__(256) void attn_row(const float* __restrict__ A,
                                                const u16* __restrict__ feat,
                                                const float* __restrict__ a_self,
                                                const float* __restrict__ a_neigh,
                                                float* __restrict__ out) {
    const int bid = blockIdx.x;
    const int row = (bid & 7) * N_ + (bid >> 3);  // XCD b <- batch b (L2 locality)
    const int b = bid & 7;
    const int t = threadIdx.x;
    const int lane = t & 63, w = t >> 6;

    __shared__ u16   lj[N_];
    __shared__ float lsv[N_];
    __shared__ int   wtot[4];
    __shared__ float wred[8];
    __shared__ float nfw[4][F_];

    const float asi = a_self[row];

    // phase 1: scan A row; per-thread contiguous 8-col segment (deterministic)
    const float4* Arow = (const float4*)(A + (size_t)row * N_);
    const float4* An   = (const float4*)(a_neigh + b * N_);
    const float4 a0 = Arow[t * 2], a1 = Arow[t * 2 + 1];
    const float4 n0 = An[t * 2],   n1 = An[t * 2 + 1];
    const float av[8] = {a0.x, a0.y, a0.z, a0.w, a1.x, a1.y, a1.z, a1.w};
    const float nv[8] = {n0.x, n0.y, n0.z, n0.w, n1.x, n1.y, n1.z, n1.w};
    float sv[8];
    int cnt = 0;
    float mloc = -3.0e38f;
#pragma unroll
    for (int e = 0; e < 8; ++e) {
        float s = asi * nv[e];
        s = s > 0.f ? s : NEG_SLOPE * s;
        sv[e] = s;
        if (av[e] != 0.f) { ++cnt; mloc = fmaxf(mloc, s); }
    }
    int v = cnt;
#pragma unroll
    for (int off = 1; off < 64; off <<= 1) {     // wave inclusive scan
        const int u = __shfl_up(v, off);
        if (lane >= off) v += u;
    }
#pragma unroll
    for (int m = 32; m; m >>= 1) mloc = fmaxf(mloc, __shfl_xor(mloc, m));
    if (lane == 63) wtot[w] = v;
    if (lane == 0) wred[w] = mloc;
    __syncthreads();
    int base = v - cnt;
#pragma unroll
    for (int i = 0; i < 4; ++i) base += (i < w) ? wtot[i] : 0;
    const int total = wtot[0] + wtot[1] + wtot[2] + wtot[3];
    const float mx = fmaxf(fmaxf(wred[0], wred[1]), fmaxf(wred[2], wred[3]));

    // phase 2: compact with fused exp + own-entry partial sum
    float ssum = 0.f;
    int pos = base;
#pragma unroll
    for (int e = 0; e < 8; ++e) {
        if (av[e] != 0.f) {
            const float wv = __expf(sv[e] - mx);
            lj[pos] = (u16)(t * 8 + e);
            lsv[pos] = wv;
            ssum += wv;
            ++pos;
        }
    }
#pragma unroll
    for (int m = 32; m; m >>= 1) ssum += __shfl_xor(ssum, m);
    if (lane == 0) wred[4 + w] = ssum;
    __syncthreads();
    const float inv = 1.f / (wred[4] + wred[5] + wred[6] + wred[7]);

    // phase 3: PV gather (f16 feat, L2-resident slab) — wave-strided entries
    const u16* frow = feat + (size_t)b * N_ * F_ + lane * 8;
    float acc[8] = {0.f, 0.f, 0.f, 0.f, 0.f, 0.f, 0.f, 0.f};
    int k = w;
    for (; k + 4 < total; k += 8) {
        const size_t j0 = (size_t)lj[k] * F_, j1 = (size_t)lj[k + 4] * F_;
        const float p0 = lsv[k], p1 = lsv[k + 4];
        const f16x8 v0 = *(const f16x8*)(frow + j0);
        const f16x8 v1 = *(const f16x8*)(frow + j1);
#pragma unroll
        for (int e = 0; e < 8; ++e) acc[e] += p0 * (float)v0[e] + p1 * (float)v1[e];
    }
    if (k < total) {
        const size_t j0 = (size_t)lj[k] * F_;
        const float p0 = lsv[k];
        const f16x8 v0 = *(const f16x8*)(frow + j0);
#pragma unroll
        for (int e = 0; e < 8; ++e) acc[e] += p0 * (float)v0[e];
    }
#pragma unroll
    for (int e = 0; e < 8; ++e) nfw[w][lane * 8 + e] = acc[e];
    __syncthreads();

    // phase 4: cross-wave sum, tanh, write 8 identical heads
    const int f0 = t * 2;
    const float nf0 = (nfw[0][f0] + nfw[1][f0]) + (nfw[2][f0] + nfw[3][f0]);
    const float nf1 = (nfw[0][f0 + 1] + nfw[1][f0 + 1]) + (nfw[2][f0 + 1] + nfw[3][f0 + 1]);
    const float o0 = tanhf(nf0 * inv);
    const float o1 = tanhf(nf1 * inv);
    const float2 o = make_float2(o0, o1);
    float* obase = out + (size_t)row * (8 * F_) + f0;
#pragma unroll
    for (int h = 0; h < 8; ++h) *(float2*)(obase + h * F_) = o;
}

extern "C" void kernel_launch(void* const* d_in, const int* in_sizes, int n_in,
                              void* d_out, int out_size, void* d_ws, size_t ws_size,
                              hipStream_t stream) {
    const float* X  = (const float*)d_in[0];
    const float* A  = (const float*)d_in[1];
    const float* Wk = (const float*)d_in[2];
    const float* bk = (const float*)d_in[3];
    const float* ws = (const float*)d_in[4];
    const float* bs = (const float*)d_in[5];
    const float* wn = (const float*)d_in[6];
    const float* bn = (const float*)d_in[7];
    float* out = (float*)d_out;

    char* wsb = (char*)d_ws;
    u16*   feat    = (u16*)(wsb);                  // 16 MiB (f16)
    u16*   Wf      = (u16*)(wsb + 16777216);       // 0.5 MiB
    float* a_self  = (float*)(wsb + 17301504);     // 64 KiB
    float* a_neigh = (float*)(wsb + 17367040);     // 64 KiB
    float* ws2     = (float*)(wsb + 17432576);     // 2 KiB
    float* wn2     = (float*)(wsb + 17434624);     // 2 KiB
    float* csn     = (float*)(wsb + 17436672);     // 8 B

    prep_all   <<<dim3(1282),  dim3(256), 0, stream>>>(Wk, bk, ws, bs, wn, bn, Wf, ws2, wn2, csn);
    gemm_feat  <<<dim3(512),   dim3(256), 0, stream>>>(X, Wf, bk, feat);
    dots_x     <<<dim3(4096),  dim3(256), 0, stream>>>(X, ws2, wn2, csn, a_self, a_neigh);
    attn_row   <<<dim3(16384), dim3(256), 0, stream>>>(A, feat, a_self, a_neigh, out);
}